// Round 7
// baseline (104.661 us; speedup 1.0000x reference)
//
#include <hip/hip_runtime.h>
#include <hip/hip_bf16.h>
#include <math.h>

// logits [8,19,256,512] f32, targets [8,256,512] int32
// R=20 truncated EDT, loss = mean_b sum_c mean_hw probs*sdf
#define NCLS 19
#define BB   8
#define HH   256
#define WW   512
#define CAP2 400u     // R^2; any d >= 21 squares past this and is capped
#define SEG  8        // rows per kA segment

typedef unsigned short u16x2 __attribute__((ext_vector_type(2)));

static __device__ __forceinline__ unsigned umin32(unsigned a, unsigned b) { return a < b ? a : b; }
static __device__ __forceinline__ float fsqrt_fast(float x) { return __builtin_amdgcn_sqrtf(x); }

// packed u16 helpers. Constants via "s" (SGPR) - scalar operand, hoisted.
static __device__ __forceinline__ unsigned pk_add_s(unsigned v, unsigned c) {
    unsigned d; asm("v_pk_add_u16 %0, %1, %2" : "=v"(d) : "s"(c), "v"(v)); return d;
}
static __device__ __forceinline__ unsigned pk_minv(unsigned a, unsigned b) {
    unsigned d; asm("v_pk_min_u16 %0, %1, %2" : "=v"(d) : "v"(a), "v"(b)); return d;
}
static __device__ __forceinline__ unsigned pk_maxv(unsigned a, unsigned b) {
    unsigned d; asm("v_pk_max_u16 %0, %1, %2" : "=v"(d) : "v"(a), "v"(b)); return d;
}
// horizontal min of the two u16 halves, replicated into both halves
static __device__ __forceinline__ unsigned pk_hmin(unsigned a) {
    unsigned d;
    asm("v_pk_min_u16 %0, %1, %1 op_sel:[1,0] op_sel_hi:[0,1]" : "=v"(d) : "v"(a));
    return d;
}
// 4 u8 distances in x -> two packed-u16 squared words
static __device__ __forceinline__ void sq8(unsigned x, unsigned& w0, unsigned& w1) {
    unsigned a = x & 0x00FF00FFu;
    unsigned b = (x >> 8) & 0x00FF00FFu;
    u16x2 sa = __builtin_bit_cast(u16x2, a); sa = sa * sa;
    u16x2 sb = __builtin_bit_cast(u16x2, b); sb = sb * sb;
    unsigned ua = __builtin_bit_cast(unsigned, sa);
    unsigned ub = __builtin_bit_cast(unsigned, sb);
    w0 = __builtin_amdgcn_perm(ub, ua, 0x05040100u);
    w1 = __builtin_amdgcn_perm(ub, ua, 0x07060302u);
}

// ---------------------------------------------------------------------------
// Kernel A: vertical pass (unchanged, passing). Thread 0 zeroes acc/cnt for
// the downstream kB accumulation (kA fully precedes kB in-stream).
// ---------------------------------------------------------------------------
__global__ __launch_bounds__(256)
void kA_vert(const int* __restrict__ targ, unsigned char* __restrict__ vneg,
             unsigned long long* __restrict__ acc, unsigned* __restrict__ cnt) {
    if (blockIdx.x == 0 && threadIdx.x == 0) { *acc = 0ULL; *cnt = 0u; }
    int gid = blockIdx.x * 256 + threadIdx.x;
    int col = gid & 4095;
    int seg = gid >> 12;
    int b = col >> 9;
    int w = col & 511;
    int h0 = seg * SEG;
    const int* tp = &targ[b * HH * WW + w];

    unsigned d[NCLS];
    unsigned pk[NCLS][2];
#pragma unroll
    for (int c = 0; c < NCLS; ++c) { d[c] = 21u; pk[c][0] = 0u; pk[c][1] = 0u; }
#pragma unroll
    for (int k = 0; k < 21 + SEG; ++k) {
        int hh = h0 - 21 + k;
        int t = -1;
        if (hh >= 0) t = tp[hh * WW];
#pragma unroll
        for (int c = 0; c < NCLS; ++c)
            d[c] = (t == c) ? 0u : d[c] + 1u;
        if (k >= 21) {
            int r = k - 21;
#pragma unroll
            for (int c = 0; c < NCLS; ++c)
                pk[c][r >> 2] |= d[c] << ((r & 3) * 8);
        }
    }
    unsigned u[NCLS];
#pragma unroll
    for (int c = 0; c < NCLS; ++c) u[c] = 21u;
#pragma unroll
    for (int k = 0; k < 21 + SEG; ++k) {
        int hh = h0 + 21 + SEG - 1 - k;
        int t = -1;
        if (hh < HH) t = tp[hh * WW];
#pragma unroll
        for (int c = 0; c < NCLS; ++c)
            u[c] = (t == c) ? 0u : u[c] + 1u;
        if (k >= 21) {
            int r = 21 + SEG - 1 - k;
#pragma unroll
            for (int c = 0; c < NCLS; ++c) {
                unsigned dv = (pk[c][r >> 2] >> ((r & 3) * 8)) & 0xffu;
                vneg[((size_t)(b * NCLS + c) * HH + hh) * WW + w] =
                    (unsigned char)umin32(dv, u[c]);
            }
        }
    }
}

// ---------------------------------------------------------------------------
// Kernel B: one BLOCK (4 waves) per row; wave w handles classes {w, w+4,...}.
// Per wave: 8 px/lane, register window via 20 ds_bpermute + halo cndmask,
// center-out cascade (exact). Partials merged in LDS: num/den/et sum, m2 min
// (exactly one wave owns the target class per px). 256 threads finalize 2 px
// each; block reduce; fixed-point atomic; LAST block writes d_out.
// ---------------------------------------------------------------------------
__global__ __launch_bounds__(256)
void kB_main(const float* __restrict__ logits, const int* __restrict__ targ,
             const unsigned char* __restrict__ vneg,
             unsigned long long* __restrict__ acc, unsigned* __restrict__ cnt,
             float* __restrict__ out) {
    __shared__ float sNum[4][512];
    __shared__ float sDen[4][512];
    __shared__ float sEt[4][512];
    __shared__ unsigned short sM2[4][512];
    __shared__ float wsum[4];
    int tid = threadIdx.x;
    int L = tid & 63;
    int wid = tid >> 6;
    int bh = blockIdx.x;               // row 0..2047
    int b = bh >> 8;
    int h = bh & 255;

    const unsigned HALO2 = 441u | (441u << 16);

#define SQx(x) ((unsigned)((x) * (x)))
#define PK2(a, bq) (SQx(a) | (SQx(bq) << 16))
    const unsigned CE[21] = {
        PK2(-20,-19), PK2(-18,-17), PK2(-16,-15), PK2(-14,-13), PK2(-12,-11),
        PK2(-10,-9),  PK2(-8,-7),   PK2(-6,-5),   PK2(-4,-3),   PK2(-2,-1),
        PK2(0,1),     PK2(2,3),     PK2(4,5),     PK2(6,7),     PK2(8,9),
        PK2(10,11),   PK2(12,13),   PK2(14,15),   PK2(16,17),   PK2(18,19),
        PK2(20,21) };
    const unsigned CO[21] = {
        PK2(-21,-20), PK2(-19,-18), PK2(-17,-16), PK2(-15,-14), PK2(-13,-12),
        PK2(-11,-10), PK2(-9,-8),   PK2(-7,-6),   PK2(-5,-4),   PK2(-3,-2),
        PK2(-1,0),    PK2(1,2),     PK2(3,4),     PK2(5,6),     PK2(7,8),
        PK2(9,10),    PK2(11,12),   PK2(13,14),   PK2(15,16),   PK2(17,18),
        PK2(19,20) };
#undef PK2
#undef SQx

    int im1 = ((L + 63) & 63) * 4, im2 = ((L + 62) & 63) * 4, im3 = ((L + 61) & 63) * 4;
    int ip1 = ((L + 1) & 63) * 4,  ip2 = ((L + 2) & 63) * 4,  ip3 = ((L + 3) & 63) * 4;

    // per-wave class subset: c = wid + 4*i
    const uint2* vrw = (const uint2*)vneg + ((size_t)(b * NCLS + wid) * HH + h) * 64 + L;
    const float* lroww = &logits[((size_t)(b * NCLS + wid) * HH + h) * WW + 8 * L];
    int nc = (wid < 3) ? 5 : 4;

    int t8[8];
    {
        const int4* tr = (const int4*)&targ[((size_t)b * HH + h) * WW + 8 * L];
        int4 ta = tr[0], tb = tr[1];
        t8[0]=ta.x; t8[1]=ta.y; t8[2]=ta.z; t8[3]=ta.w;
        t8[4]=tb.x; t8[5]=tb.y; t8[6]=tb.z; t8[7]=tb.w;
    }

    float den[8], num[8], et[8];
    unsigned m2[8];
#pragma unroll
    for (int p = 0; p < 8; ++p) { den[p]=0.f; num[p]=0.f; et[p]=0.f; m2[p]=0xFFFFu; }

    uint2 v8n = vrw[0];
    float4 f0n = *(const float4*)lroww;
    float4 f1n = *(const float4*)(lroww + 4);

#pragma unroll 1
    for (int i = 0; i < nc; ++i) {
        int c = wid + 4 * i;
        uint2 v8 = v8n;
        float4 f0 = f0n, f1 = f1n;
        if (i + 1 < nc) {
            size_t off = (size_t)(i + 1) * 4 * (HH * 64);
            v8n = vrw[off];
            const float* ln = lroww + (size_t)(i + 1) * 4 * (HH * WW);
            f0n = *(const float4*)ln;
            f1n = *(const float4*)(ln + 4);
        }

        unsigned o0, o1, o2, o3;
        sq8(v8.x, o0, o1);
        sq8(v8.y, o2, o3);

        unsigned S[24];
        S[10] = o0; S[11] = o1; S[12] = o2; S[13] = o3;
        unsigned t;
        t = __builtin_amdgcn_ds_bpermute(im1, (int)o3); S[9]  = (L >= 1) ? t : HALO2;
        t = __builtin_amdgcn_ds_bpermute(im1, (int)o2); S[8]  = (L >= 1) ? t : HALO2;
        t = __builtin_amdgcn_ds_bpermute(im1, (int)o1); S[7]  = (L >= 1) ? t : HALO2;
        t = __builtin_amdgcn_ds_bpermute(im1, (int)o0); S[6]  = (L >= 1) ? t : HALO2;
        t = __builtin_amdgcn_ds_bpermute(im2, (int)o3); S[5]  = (L >= 2) ? t : HALO2;
        t = __builtin_amdgcn_ds_bpermute(im2, (int)o2); S[4]  = (L >= 2) ? t : HALO2;
        t = __builtin_amdgcn_ds_bpermute(im2, (int)o1); S[3]  = (L >= 2) ? t : HALO2;
        t = __builtin_amdgcn_ds_bpermute(im2, (int)o0); S[2]  = (L >= 2) ? t : HALO2;
        t = __builtin_amdgcn_ds_bpermute(im3, (int)o3); S[1]  = (L >= 3) ? t : HALO2;
        t = __builtin_amdgcn_ds_bpermute(im3, (int)o2); S[0]  = (L >= 3) ? t : HALO2;
        t = __builtin_amdgcn_ds_bpermute(ip1, (int)o0); S[14] = (L <= 62) ? t : HALO2;
        t = __builtin_amdgcn_ds_bpermute(ip1, (int)o1); S[15] = (L <= 62) ? t : HALO2;
        t = __builtin_amdgcn_ds_bpermute(ip1, (int)o2); S[16] = (L <= 62) ? t : HALO2;
        t = __builtin_amdgcn_ds_bpermute(ip1, (int)o3); S[17] = (L <= 62) ? t : HALO2;
        t = __builtin_amdgcn_ds_bpermute(ip2, (int)o0); S[18] = (L <= 61) ? t : HALO2;
        t = __builtin_amdgcn_ds_bpermute(ip2, (int)o1); S[19] = (L <= 61) ? t : HALO2;
        t = __builtin_amdgcn_ds_bpermute(ip2, (int)o2); S[20] = (L <= 61) ? t : HALO2;
        t = __builtin_amdgcn_ds_bpermute(ip2, (int)o3); S[21] = (L <= 61) ? t : HALO2;
        t = __builtin_amdgcn_ds_bpermute(ip3, (int)o0); S[22] = (L <= 60) ? t : HALO2;
        t = __builtin_amdgcn_ds_bpermute(ip3, (int)o1); S[23] = (L <= 60) ? t : HALO2;

        unsigned ae[4], ao[4];
#pragma unroll
        for (int r = 0; r < 4; ++r) { ae[r] = 0xFFFFFFFFu; ao[r] = 0xFFFFFFFFu; }

        // center band m=7..13; skip rest if all partial mins <= 49
#pragma unroll
        for (int r = 0; r < 4; ++r)
#pragma unroll
            for (int m = 7; m <= 13; ++m) {
                ae[r] = pk_minv(ae[r], pk_add_s(S[r + m], CE[m]));
                ao[r] = pk_minv(ao[r], pk_add_s(S[r + m], CO[m]));
            }

        unsigned mx = pk_maxv(pk_maxv(pk_maxv(pk_hmin(ae[0]), pk_hmin(ao[0])),
                                      pk_maxv(pk_hmin(ae[1]), pk_hmin(ao[1]))),
                              pk_maxv(pk_maxv(pk_hmin(ae[2]), pk_hmin(ao[2])),
                                      pk_maxv(pk_hmin(ae[3]), pk_hmin(ao[3]))));
        if (!__all(mx <= (49u | (49u << 16)))) {
            // band2 m in {4..6, 14..16} (remaining dx^2 >= 49)
#pragma unroll
            for (int r = 0; r < 4; ++r) {
#pragma unroll
                for (int m = 4; m <= 6; ++m) {
                    ae[r] = pk_minv(ae[r], pk_add_s(S[r + m], CE[m]));
                    ao[r] = pk_minv(ao[r], pk_add_s(S[r + m], CO[m]));
                }
#pragma unroll
                for (int m = 14; m <= 16; ++m) {
                    ae[r] = pk_minv(ae[r], pk_add_s(S[r + m], CE[m]));
                    ao[r] = pk_minv(ao[r], pk_add_s(S[r + m], CO[m]));
                }
            }
            mx = pk_maxv(pk_maxv(pk_maxv(pk_hmin(ae[0]), pk_hmin(ao[0])),
                                 pk_maxv(pk_hmin(ae[1]), pk_hmin(ao[1]))),
                         pk_maxv(pk_maxv(pk_hmin(ae[2]), pk_hmin(ao[2])),
                                 pk_maxv(pk_hmin(ae[3]), pk_hmin(ao[3]))));
            if (!__all(mx <= (169u | (169u << 16)))) {
                // band3 m in {0..3, 17..20} (remaining dx^2 >= 169)
#pragma unroll
                for (int r = 0; r < 4; ++r) {
#pragma unroll
                    for (int m = 0; m <= 3; ++m) {
                        ae[r] = pk_minv(ae[r], pk_add_s(S[r + m], CE[m]));
                        ao[r] = pk_minv(ao[r], pk_add_s(S[r + m], CO[m]));
                    }
#pragma unroll
                    for (int m = 17; m <= 20; ++m) {
                        ae[r] = pk_minv(ae[r], pk_add_s(S[r + m], CE[m]));
                        ao[r] = pk_minv(ao[r], pk_add_s(S[r + m], CO[m]));
                    }
                }
            }
        }

        float fx[8] = {f0.x, f0.y, f0.z, f0.w, f1.x, f1.y, f1.z, f1.w};
#pragma unroll
        for (int r = 0; r < 4; ++r) {
            unsigned nd0 = pk_hmin(ae[r]) & 0xFFFFu;   // px 8L+2r
            unsigned nd1 = pk_hmin(ao[r]) & 0xFFFFu;   // px 8L+2r+1
            float e0 = __expf(fx[2 * r]), e1 = __expf(fx[2 * r + 1]);
            den[2 * r] += e0; den[2 * r + 1] += e1;
            bool is0 = (c == t8[2 * r]), is1 = (c == t8[2 * r + 1]);
            float s0 = fsqrt_fast((float)umin32(nd0, CAP2));
            float s1 = fsqrt_fast((float)umin32(nd1, CAP2));
            num[2 * r]     += is0 ? 0.f : e0 * s0;
            num[2 * r + 1] += is1 ? 0.f : e1 * s1;
            et[2 * r]     = is0 ? e0 : et[2 * r];
            et[2 * r + 1] = is1 ? e1 : et[2 * r + 1];
            m2[2 * r]     = umin32(m2[2 * r],     is0 ? 0xFFFFu : nd0);
            m2[2 * r + 1] = umin32(m2[2 * r + 1], is1 ? 0xFFFFu : nd1);
        }
    }

    // ---- merge partials across the 4 waves ----
    *(float4*)&sNum[wid][8 * L]     = (float4){num[0], num[1], num[2], num[3]};
    *(float4*)&sNum[wid][8 * L + 4] = (float4){num[4], num[5], num[6], num[7]};
    *(float4*)&sDen[wid][8 * L]     = (float4){den[0], den[1], den[2], den[3]};
    *(float4*)&sDen[wid][8 * L + 4] = (float4){den[4], den[5], den[6], den[7]};
    *(float4*)&sEt[wid][8 * L]      = (float4){et[0], et[1], et[2], et[3]};
    *(float4*)&sEt[wid][8 * L + 4]  = (float4){et[4], et[5], et[6], et[7]};
    uint4 mq;
    mq.x = m2[0] | (m2[1] << 16); mq.y = m2[2] | (m2[3] << 16);
    mq.z = m2[4] | (m2[5] << 16); mq.w = m2[6] | (m2[7] << 16);
    *(uint4*)&sM2[wid][8 * L] = mq;
    __syncthreads();

    // each thread finalizes 2 pixels (2tid, 2tid+1)
    float v;
    {
        int px = 2 * tid;
        float2 n0 = *(const float2*)&sNum[0][px], n1 = *(const float2*)&sNum[1][px];
        float2 n2 = *(const float2*)&sNum[2][px], n3 = *(const float2*)&sNum[3][px];
        float2 d0 = *(const float2*)&sDen[0][px], d1 = *(const float2*)&sDen[1][px];
        float2 d2 = *(const float2*)&sDen[2][px], d3 = *(const float2*)&sDen[3][px];
        float2 e0 = *(const float2*)&sEt[0][px],  e1 = *(const float2*)&sEt[1][px];
        float2 e2 = *(const float2*)&sEt[2][px],  e3 = *(const float2*)&sEt[3][px];
        unsigned q0 = *(const unsigned*)&sM2[0][px], q1 = *(const unsigned*)&sM2[1][px];
        unsigned q2 = *(const unsigned*)&sM2[2][px], q3 = *(const unsigned*)&sM2[3][px];
        float N0 = (n0.x + n1.x) + (n2.x + n3.x);
        float N1 = (n0.y + n1.y) + (n2.y + n3.y);
        float D0 = (d0.x + d1.x) + (d2.x + d3.x);
        float D1 = (d0.y + d1.y) + (d2.y + d3.y);
        float E0 = (e0.x + e1.x) + (e2.x + e3.x);
        float E1 = (e0.y + e1.y) + (e2.y + e3.y);
        unsigned M0 = umin32(umin32(q0 & 0xFFFFu, q1 & 0xFFFFu),
                             umin32(q2 & 0xFFFFu, q3 & 0xFFFFu));
        unsigned M1 = umin32(umin32(q0 >> 16, q1 >> 16), umin32(q2 >> 16, q3 >> 16));
        v = (N0 - E0 * fsqrt_fast((float)umin32(M0, CAP2))) / D0
          + (N1 - E1 * fsqrt_fast((float)umin32(M1, CAP2))) / D1;
    }

#pragma unroll
    for (int off = 32; off >= 1; off >>= 1) v += __shfl_down(v, off);
    if ((tid & 63) == 0) wsum[wid] = v;
    __syncthreads();
    if (tid == 0) {
        float s = (wsum[0] + wsum[1]) + (wsum[2] + wsum[3]);
        // fixed-point 2^36 with /20 folded in; integer atomic => deterministic
        double q = (double)s * (68719476736.0 / 20.0);
        atomicAdd(acc, (unsigned long long)(long long)q);
        __threadfence();
        unsigned prev = atomicAdd(cnt, 1u);
        if (prev == gridDim.x - 1) {            // last block finalizes
            unsigned long long tot = atomicAdd(acc, 0ULL);
            double vv = (double)(long long)tot / 68719476736.0;
            out[0] = (float)(vv / (double)((size_t)BB * HH * WW));
        }
    }
}

extern "C" void kernel_launch(void* const* d_in, const int* in_sizes, int n_in,
                              void* d_out, int out_size, void* d_ws, size_t ws_size,
                              hipStream_t stream) {
    const float* logits = (const float*)d_in[0];
    const int* targ = (const int*)d_in[1];
    unsigned char* wsb = (unsigned char*)d_ws;
    unsigned long long* acc = (unsigned long long*)wsb;       // [0,8)
    unsigned* cnt = (unsigned*)(wsb + 8);                     // [8,12)
    unsigned char* vneg = wsb + 64;                           // 19.9 MB u8

    kA_vert<<<512, 256, 0, stream>>>(targ, vneg, acc, cnt);   // zeroes acc/cnt
    kB_main<<<BB * HH, 256, 0, stream>>>(logits, targ, vneg, acc, cnt,
                                         (float*)d_out);      // 1 block/row
}

// Round 8
// 60.260 us; speedup vs baseline: 1.7368x; 1.7368x over previous
//
#include <hip/hip_runtime.h>
#include <hip/hip_bf16.h>
#include <math.h>

// logits [8,19,256,512] f32, targets [8,256,512] int32
// R=20 truncated EDT, loss = mean_b sum_c mean_hw probs*sdf
#define NCLS 19
#define BB   8
#define HH   256
#define WW   512
#define CAP2 400u     // R^2; any d >= 21 squares past this and is capped
#define SEG  8        // rows per kA segment

typedef unsigned short u16x2 __attribute__((ext_vector_type(2)));

static __device__ __forceinline__ unsigned umin32(unsigned a, unsigned b) { return a < b ? a : b; }
static __device__ __forceinline__ float fsqrt_fast(float x) { return __builtin_amdgcn_sqrtf(x); }

// packed u16 helpers. Constants via "s" (SGPR) - scalar operand, hoisted.
static __device__ __forceinline__ unsigned pk_add_s(unsigned v, unsigned c) {
    unsigned d; asm("v_pk_add_u16 %0, %1, %2" : "=v"(d) : "s"(c), "v"(v)); return d;
}
static __device__ __forceinline__ unsigned pk_minv(unsigned a, unsigned b) {
    unsigned d; asm("v_pk_min_u16 %0, %1, %2" : "=v"(d) : "v"(a), "v"(b)); return d;
}
static __device__ __forceinline__ unsigned pk_maxv(unsigned a, unsigned b) {
    unsigned d; asm("v_pk_max_u16 %0, %1, %2" : "=v"(d) : "v"(a), "v"(b)); return d;
}
// horizontal min of the two u16 halves, replicated into both halves
static __device__ __forceinline__ unsigned pk_hmin(unsigned a) {
    unsigned d;
    asm("v_pk_min_u16 %0, %1, %1 op_sel:[1,0] op_sel_hi:[0,1]" : "=v"(d) : "v"(a));
    return d;
}
// 4 u8 distances in x -> two packed-u16 squared words
static __device__ __forceinline__ void sq8(unsigned x, unsigned& w0, unsigned& w1) {
    unsigned a = x & 0x00FF00FFu;
    unsigned b = (x >> 8) & 0x00FF00FFu;
    u16x2 sa = __builtin_bit_cast(u16x2, a); sa = sa * sa;
    u16x2 sb = __builtin_bit_cast(u16x2, b); sb = sb * sb;
    unsigned ua = __builtin_bit_cast(unsigned, sa);
    unsigned ub = __builtin_bit_cast(unsigned, sb);
    w0 = __builtin_amdgcn_perm(ub, ua, 0x05040100u);
    w1 = __builtin_amdgcn_perm(ub, ua, 0x07060302u);
}

// ---------------------------------------------------------------------------
// Kernel A: vertical pass (unchanged, passing). Thread 0 zeroes acc for the
// downstream kB accumulation (kA fully precedes kB in-stream).
// ---------------------------------------------------------------------------
__global__ __launch_bounds__(256)
void kA_vert(const int* __restrict__ targ, unsigned char* __restrict__ vneg,
             unsigned long long* __restrict__ acc) {
    if (blockIdx.x == 0 && threadIdx.x == 0) { *acc = 0ULL; }
    int gid = blockIdx.x * 256 + threadIdx.x;
    int col = gid & 4095;
    int seg = gid >> 12;
    int b = col >> 9;
    int w = col & 511;
    int h0 = seg * SEG;
    const int* tp = &targ[b * HH * WW + w];

    unsigned d[NCLS];
    unsigned pk[NCLS][2];
#pragma unroll
    for (int c = 0; c < NCLS; ++c) { d[c] = 21u; pk[c][0] = 0u; pk[c][1] = 0u; }
#pragma unroll
    for (int k = 0; k < 21 + SEG; ++k) {
        int hh = h0 - 21 + k;
        int t = -1;
        if (hh >= 0) t = tp[hh * WW];
#pragma unroll
        for (int c = 0; c < NCLS; ++c)
            d[c] = (t == c) ? 0u : d[c] + 1u;
        if (k >= 21) {
            int r = k - 21;
#pragma unroll
            for (int c = 0; c < NCLS; ++c)
                pk[c][r >> 2] |= d[c] << ((r & 3) * 8);
        }
    }
    unsigned u[NCLS];
#pragma unroll
    for (int c = 0; c < NCLS; ++c) u[c] = 21u;
#pragma unroll
    for (int k = 0; k < 21 + SEG; ++k) {
        int hh = h0 + 21 + SEG - 1 - k;
        int t = -1;
        if (hh < HH) t = tp[hh * WW];
#pragma unroll
        for (int c = 0; c < NCLS; ++c)
            u[c] = (t == c) ? 0u : u[c] + 1u;
        if (k >= 21) {
            int r = 21 + SEG - 1 - k;
#pragma unroll
            for (int c = 0; c < NCLS; ++c) {
                unsigned dv = (pk[c][r >> 2] >> ((r & 3) * 8)) & 0xffu;
                vneg[((size_t)(b * NCLS + c) * HH + hh) * WW + w] =
                    (unsigned char)umin32(dv, u[c]);
            }
        }
    }
}

// ---------------------------------------------------------------------------
// Kernel B: one BLOCK (4 waves) per row; wave w handles classes {w, w+4,...}.
// Per wave: 8 px/lane, register window via 20 ds_bpermute + halo cndmask,
// center-out cascade (exact). Partials merged in LDS: num/den/et sum, m2 min
// (exactly one wave owns the target class per px). 256 threads finalize 2 px
// each; block reduce; fixed-point atomic. NO fence/finalize here (a per-block
// __threadfence L2-writeback poisoned L2 in round 7: VALUBusy 43->17%).
// ---------------------------------------------------------------------------
__global__ __launch_bounds__(256)
void kB_main(const float* __restrict__ logits, const int* __restrict__ targ,
             const unsigned char* __restrict__ vneg,
             unsigned long long* __restrict__ acc) {
    __shared__ float sNum[4][512];
    __shared__ float sDen[4][512];
    __shared__ float sEt[4][512];
    __shared__ unsigned short sM2[4][512];
    __shared__ float wsum[4];
    int tid = threadIdx.x;
    int L = tid & 63;
    int wid = tid >> 6;
    int bh = blockIdx.x;               // row 0..2047
    int b = bh >> 8;
    int h = bh & 255;

    const unsigned HALO2 = 441u | (441u << 16);

#define SQx(x) ((unsigned)((x) * (x)))
#define PK2(a, bq) (SQx(a) | (SQx(bq) << 16))
    const unsigned CE[21] = {
        PK2(-20,-19), PK2(-18,-17), PK2(-16,-15), PK2(-14,-13), PK2(-12,-11),
        PK2(-10,-9),  PK2(-8,-7),   PK2(-6,-5),   PK2(-4,-3),   PK2(-2,-1),
        PK2(0,1),     PK2(2,3),     PK2(4,5),     PK2(6,7),     PK2(8,9),
        PK2(10,11),   PK2(12,13),   PK2(14,15),   PK2(16,17),   PK2(18,19),
        PK2(20,21) };
    const unsigned CO[21] = {
        PK2(-21,-20), PK2(-19,-18), PK2(-17,-16), PK2(-15,-14), PK2(-13,-12),
        PK2(-11,-10), PK2(-9,-8),   PK2(-7,-6),   PK2(-5,-4),   PK2(-3,-2),
        PK2(-1,0),    PK2(1,2),     PK2(3,4),     PK2(5,6),     PK2(7,8),
        PK2(9,10),    PK2(11,12),   PK2(13,14),   PK2(15,16),   PK2(17,18),
        PK2(19,20) };
#undef PK2
#undef SQx

    int im1 = ((L + 63) & 63) * 4, im2 = ((L + 62) & 63) * 4, im3 = ((L + 61) & 63) * 4;
    int ip1 = ((L + 1) & 63) * 4,  ip2 = ((L + 2) & 63) * 4,  ip3 = ((L + 3) & 63) * 4;

    // per-wave class subset: c = wid + 4*i
    const uint2* vrw = (const uint2*)vneg + ((size_t)(b * NCLS + wid) * HH + h) * 64 + L;
    const float* lroww = &logits[((size_t)(b * NCLS + wid) * HH + h) * WW + 8 * L];
    int nc = (wid < 3) ? 5 : 4;

    int t8[8];
    {
        const int4* tr = (const int4*)&targ[((size_t)b * HH + h) * WW + 8 * L];
        int4 ta = tr[0], tb = tr[1];
        t8[0]=ta.x; t8[1]=ta.y; t8[2]=ta.z; t8[3]=ta.w;
        t8[4]=tb.x; t8[5]=tb.y; t8[6]=tb.z; t8[7]=tb.w;
    }

    float den[8], num[8], et[8];
    unsigned m2[8];
#pragma unroll
    for (int p = 0; p < 8; ++p) { den[p]=0.f; num[p]=0.f; et[p]=0.f; m2[p]=0xFFFFu; }

    uint2 v8n = vrw[0];
    float4 f0n = *(const float4*)lroww;
    float4 f1n = *(const float4*)(lroww + 4);

#pragma unroll 1
    for (int i = 0; i < nc; ++i) {
        int c = wid + 4 * i;
        uint2 v8 = v8n;
        float4 f0 = f0n, f1 = f1n;
        if (i + 1 < nc) {
            size_t off = (size_t)(i + 1) * 4 * (HH * 64);
            v8n = vrw[off];
            const float* ln = lroww + (size_t)(i + 1) * 4 * (HH * WW);
            f0n = *(const float4*)ln;
            f1n = *(const float4*)(ln + 4);
        }

        unsigned o0, o1, o2, o3;
        sq8(v8.x, o0, o1);
        sq8(v8.y, o2, o3);

        unsigned S[24];
        S[10] = o0; S[11] = o1; S[12] = o2; S[13] = o3;
        unsigned t;
        t = __builtin_amdgcn_ds_bpermute(im1, (int)o3); S[9]  = (L >= 1) ? t : HALO2;
        t = __builtin_amdgcn_ds_bpermute(im1, (int)o2); S[8]  = (L >= 1) ? t : HALO2;
        t = __builtin_amdgcn_ds_bpermute(im1, (int)o1); S[7]  = (L >= 1) ? t : HALO2;
        t = __builtin_amdgcn_ds_bpermute(im1, (int)o0); S[6]  = (L >= 1) ? t : HALO2;
        t = __builtin_amdgcn_ds_bpermute(im2, (int)o3); S[5]  = (L >= 2) ? t : HALO2;
        t = __builtin_amdgcn_ds_bpermute(im2, (int)o2); S[4]  = (L >= 2) ? t : HALO2;
        t = __builtin_amdgcn_ds_bpermute(im2, (int)o1); S[3]  = (L >= 2) ? t : HALO2;
        t = __builtin_amdgcn_ds_bpermute(im2, (int)o0); S[2]  = (L >= 2) ? t : HALO2;
        t = __builtin_amdgcn_ds_bpermute(im3, (int)o3); S[1]  = (L >= 3) ? t : HALO2;
        t = __builtin_amdgcn_ds_bpermute(im3, (int)o2); S[0]  = (L >= 3) ? t : HALO2;
        t = __builtin_amdgcn_ds_bpermute(ip1, (int)o0); S[14] = (L <= 62) ? t : HALO2;
        t = __builtin_amdgcn_ds_bpermute(ip1, (int)o1); S[15] = (L <= 62) ? t : HALO2;
        t = __builtin_amdgcn_ds_bpermute(ip1, (int)o2); S[16] = (L <= 62) ? t : HALO2;
        t = __builtin_amdgcn_ds_bpermute(ip1, (int)o3); S[17] = (L <= 62) ? t : HALO2;
        t = __builtin_amdgcn_ds_bpermute(ip2, (int)o0); S[18] = (L <= 61) ? t : HALO2;
        t = __builtin_amdgcn_ds_bpermute(ip2, (int)o1); S[19] = (L <= 61) ? t : HALO2;
        t = __builtin_amdgcn_ds_bpermute(ip2, (int)o2); S[20] = (L <= 61) ? t : HALO2;
        t = __builtin_amdgcn_ds_bpermute(ip2, (int)o3); S[21] = (L <= 61) ? t : HALO2;
        t = __builtin_amdgcn_ds_bpermute(ip3, (int)o0); S[22] = (L <= 60) ? t : HALO2;
        t = __builtin_amdgcn_ds_bpermute(ip3, (int)o1); S[23] = (L <= 60) ? t : HALO2;

        unsigned ae[4], ao[4];
#pragma unroll
        for (int r = 0; r < 4; ++r) { ae[r] = 0xFFFFFFFFu; ao[r] = 0xFFFFFFFFu; }

        // center band m=7..13; skip rest if all partial mins <= 49
#pragma unroll
        for (int r = 0; r < 4; ++r)
#pragma unroll
            for (int m = 7; m <= 13; ++m) {
                ae[r] = pk_minv(ae[r], pk_add_s(S[r + m], CE[m]));
                ao[r] = pk_minv(ao[r], pk_add_s(S[r + m], CO[m]));
            }

        unsigned mx = pk_maxv(pk_maxv(pk_maxv(pk_hmin(ae[0]), pk_hmin(ao[0])),
                                      pk_maxv(pk_hmin(ae[1]), pk_hmin(ao[1]))),
                              pk_maxv(pk_maxv(pk_hmin(ae[2]), pk_hmin(ao[2])),
                                      pk_maxv(pk_hmin(ae[3]), pk_hmin(ao[3]))));
        if (!__all(mx <= (49u | (49u << 16)))) {
            // band2 m in {4..6, 14..16} (remaining dx^2 >= 49)
#pragma unroll
            for (int r = 0; r < 4; ++r) {
#pragma unroll
                for (int m = 4; m <= 6; ++m) {
                    ae[r] = pk_minv(ae[r], pk_add_s(S[r + m], CE[m]));
                    ao[r] = pk_minv(ao[r], pk_add_s(S[r + m], CO[m]));
                }
#pragma unroll
                for (int m = 14; m <= 16; ++m) {
                    ae[r] = pk_minv(ae[r], pk_add_s(S[r + m], CE[m]));
                    ao[r] = pk_minv(ao[r], pk_add_s(S[r + m], CO[m]));
                }
            }
            mx = pk_maxv(pk_maxv(pk_maxv(pk_hmin(ae[0]), pk_hmin(ao[0])),
                                 pk_maxv(pk_hmin(ae[1]), pk_hmin(ao[1]))),
                         pk_maxv(pk_maxv(pk_hmin(ae[2]), pk_hmin(ao[2])),
                                 pk_maxv(pk_hmin(ae[3]), pk_hmin(ao[3]))));
            if (!__all(mx <= (169u | (169u << 16)))) {
                // band3 m in {0..3, 17..20} (remaining dx^2 >= 169)
#pragma unroll
                for (int r = 0; r < 4; ++r) {
#pragma unroll
                    for (int m = 0; m <= 3; ++m) {
                        ae[r] = pk_minv(ae[r], pk_add_s(S[r + m], CE[m]));
                        ao[r] = pk_minv(ao[r], pk_add_s(S[r + m], CO[m]));
                    }
#pragma unroll
                    for (int m = 17; m <= 20; ++m) {
                        ae[r] = pk_minv(ae[r], pk_add_s(S[r + m], CE[m]));
                        ao[r] = pk_minv(ao[r], pk_add_s(S[r + m], CO[m]));
                    }
                }
            }
        }

        float fx[8] = {f0.x, f0.y, f0.z, f0.w, f1.x, f1.y, f1.z, f1.w};
#pragma unroll
        for (int r = 0; r < 4; ++r) {
            unsigned nd0 = pk_hmin(ae[r]) & 0xFFFFu;   // px 8L+2r
            unsigned nd1 = pk_hmin(ao[r]) & 0xFFFFu;   // px 8L+2r+1
            float e0 = __expf(fx[2 * r]), e1 = __expf(fx[2 * r + 1]);
            den[2 * r] += e0; den[2 * r + 1] += e1;
            bool is0 = (c == t8[2 * r]), is1 = (c == t8[2 * r + 1]);
            float s0 = fsqrt_fast((float)umin32(nd0, CAP2));
            float s1 = fsqrt_fast((float)umin32(nd1, CAP2));
            num[2 * r]     += is0 ? 0.f : e0 * s0;
            num[2 * r + 1] += is1 ? 0.f : e1 * s1;
            et[2 * r]     = is0 ? e0 : et[2 * r];
            et[2 * r + 1] = is1 ? e1 : et[2 * r + 1];
            m2[2 * r]     = umin32(m2[2 * r],     is0 ? 0xFFFFu : nd0);
            m2[2 * r + 1] = umin32(m2[2 * r + 1], is1 ? 0xFFFFu : nd1);
        }
    }

    // ---- merge partials across the 4 waves ----
    *(float4*)&sNum[wid][8 * L]     = (float4){num[0], num[1], num[2], num[3]};
    *(float4*)&sNum[wid][8 * L + 4] = (float4){num[4], num[5], num[6], num[7]};
    *(float4*)&sDen[wid][8 * L]     = (float4){den[0], den[1], den[2], den[3]};
    *(float4*)&sDen[wid][8 * L + 4] = (float4){den[4], den[5], den[6], den[7]};
    *(float4*)&sEt[wid][8 * L]      = (float4){et[0], et[1], et[2], et[3]};
    *(float4*)&sEt[wid][8 * L + 4]  = (float4){et[4], et[5], et[6], et[7]};
    uint4 mq;
    mq.x = m2[0] | (m2[1] << 16); mq.y = m2[2] | (m2[3] << 16);
    mq.z = m2[4] | (m2[5] << 16); mq.w = m2[6] | (m2[7] << 16);
    *(uint4*)&sM2[wid][8 * L] = mq;
    __syncthreads();

    // each thread finalizes 2 pixels (2tid, 2tid+1)
    float v;
    {
        int px = 2 * tid;
        float2 n0 = *(const float2*)&sNum[0][px], n1 = *(const float2*)&sNum[1][px];
        float2 n2 = *(const float2*)&sNum[2][px], n3 = *(const float2*)&sNum[3][px];
        float2 d0 = *(const float2*)&sDen[0][px], d1 = *(const float2*)&sDen[1][px];
        float2 d2 = *(const float2*)&sDen[2][px], d3 = *(const float2*)&sDen[3][px];
        float2 e0 = *(const float2*)&sEt[0][px],  e1 = *(const float2*)&sEt[1][px];
        float2 e2 = *(const float2*)&sEt[2][px],  e3 = *(const float2*)&sEt[3][px];
        unsigned q0 = *(const unsigned*)&sM2[0][px], q1 = *(const unsigned*)&sM2[1][px];
        unsigned q2 = *(const unsigned*)&sM2[2][px], q3 = *(const unsigned*)&sM2[3][px];
        float N0 = (n0.x + n1.x) + (n2.x + n3.x);
        float N1 = (n0.y + n1.y) + (n2.y + n3.y);
        float D0 = (d0.x + d1.x) + (d2.x + d3.x);
        float D1 = (d0.y + d1.y) + (d2.y + d3.y);
        float E0 = (e0.x + e1.x) + (e2.x + e3.x);
        float E1 = (e0.y + e1.y) + (e2.y + e3.y);
        unsigned M0 = umin32(umin32(q0 & 0xFFFFu, q1 & 0xFFFFu),
                             umin32(q2 & 0xFFFFu, q3 & 0xFFFFu));
        unsigned M1 = umin32(umin32(q0 >> 16, q1 >> 16), umin32(q2 >> 16, q3 >> 16));
        v = (N0 - E0 * fsqrt_fast((float)umin32(M0, CAP2))) / D0
          + (N1 - E1 * fsqrt_fast((float)umin32(M1, CAP2))) / D1;
    }

#pragma unroll
    for (int off = 32; off >= 1; off >>= 1) v += __shfl_down(v, off);
    if ((tid & 63) == 0) wsum[wid] = v;
    __syncthreads();
    if (tid == 0) {
        float s = (wsum[0] + wsum[1]) + (wsum[2] + wsum[3]);
        // fixed-point 2^36 with /20 folded in; integer atomic => deterministic
        double q = (double)s * (68719476736.0 / 20.0);
        atomicAdd(acc, (unsigned long long)(long long)q);
    }
}

__global__ void kC_final(const unsigned long long* __restrict__ acc,
                         float* __restrict__ out) {
    long long iv = (long long)*acc;
    double v = (double)iv / 68719476736.0;
    out[0] = (float)(v / (double)((size_t)BB * HH * WW));
}

extern "C" void kernel_launch(void* const* d_in, const int* in_sizes, int n_in,
                              void* d_out, int out_size, void* d_ws, size_t ws_size,
                              hipStream_t stream) {
    const float* logits = (const float*)d_in[0];
    const int* targ = (const int*)d_in[1];
    unsigned char* wsb = (unsigned char*)d_ws;
    unsigned long long* acc = (unsigned long long*)wsb;       // [0,8)
    unsigned char* vneg = wsb + 64;                           // 19.9 MB u8

    kA_vert<<<512, 256, 0, stream>>>(targ, vneg, acc);        // zeroes acc
    kB_main<<<BB * HH, 256, 0, stream>>>(logits, targ, vneg, acc);
    kC_final<<<1, 1, 0, stream>>>(acc, (float*)d_out);
}